// Round 11
// baseline (127.751 us; speedup 1.0000x reference)
//
#include <hip/hip_runtime.h>
#include <hip/hip_bf16.h>
#include <math.h>

// Problem constants
#define Bc 8
#define Nc 512
#define Tc 64
#define Cc 128
#define Mc 32
#define MEMc 20
#define Ec 4

// LDS strides (bf16 elements)
#define LDK  40   // sh_k  [64][40]
#define LDVT 72   // sh_vt [32][72]

#define UNITS 8   // bn-units per block, straight-line unrolled

typedef short bf16x8 __attribute__((ext_vector_type(8)));
typedef float f32x4  __attribute__((ext_vector_type(4)));

__device__ __forceinline__ unsigned short f2bfu(float f) {
    return __builtin_bit_cast(unsigned short, __float2bfloat16(f));
}
__device__ __forceinline__ unsigned pk2bf(float x, float y) {
    return ((unsigned)f2bfu(y) << 16) | (unsigned)f2bfu(x);
}

// global->LDS direct DMA, 16 B per lane (dest = uniform base + lane*16)
__device__ __forceinline__ void gload_lds16(const void* g, void* l) {
    __builtin_amdgcn_global_load_lds(
        (const __attribute__((address_space(1))) unsigned int*)g,
        (__attribute__((address_space(3))) unsigned int*)l, 16, 0, 0);
}

// ---- prep (blocks 0..191): swizzled bf16 weight image wt_img[e][mat][m][c ^ ((m&7)<<3)]
//      block 192: bankM[m][k] bf16 (K zero-padded to 32) + G2[k][2] = iq @ membank^T.
__global__ void prep(const float* __restrict__ Wq, const float* __restrict__ Wk,
                     const float* __restrict__ Wv, const float* __restrict__ membank,
                     const float* __restrict__ iq,
                     short* __restrict__ wt_img, short* __restrict__ bankM,
                     float* __restrict__ G2) {
    const int t = threadIdx.x;
    if (blockIdx.x < 192) {
        int idx = blockIdx.x * 256 + t;                 // 49152 = 4*3*32*128
        int e   = idx / 12288;
        int r   = idx - e * 12288;
        int mat = r >> 12;
        int m   = (r >> 7) & 31;
        int c   = r & 127;
        const float* W = (mat == 0) ? Wq : (mat == 1) ? Wk : Wv;
        const int dst = e * 12288 + mat * 4096 + m * 128 + (c ^ ((m & 7) << 3));
        wt_img[dst] = (short)f2bfu(W[((size_t)e * Cc + c) * Mc + m]);
    } else {
        for (int idx = t; idx < Mc * 32; idx += 256) {
            int m = idx >> 5, k = idx & 31;
            bankM[idx] = (short)f2bfu((k < MEMc) ? membank[k * Mc + m] : 0.f);
        }
        if (t < MEMc) {
            float g0 = 0.f, g1 = 0.f;
            for (int m = 0; m < Mc; ++m) {
                float b = membank[t * Mc + m];
                g0 = fmaf(iq[m], b, g0);
                g1 = fmaf(iq[Mc + m], b, g1);
            }
            G2[2 * t]     = g0;
            G2[2 * t + 1] = g1;
        }
    }
}

// ---- hidden tile row load (8 x dwordx4) / convert to bf16 A-frags
__device__ __forceinline__ void load_hidden(const float* __restrict__ hrow, float4 h[8]) {
    #pragma unroll
    for (int kt = 0; kt < 4; ++kt) {
        h[2 * kt]     = *(const float4*)(hrow + kt * 32);
        h[2 * kt + 1] = *(const float4*)(hrow + kt * 32 + 4);
    }
}
__device__ __forceinline__ void conv_a(const float4 h[8], bf16x8 a[4]) {
    #pragma unroll
    for (int kt = 0; kt < 4; ++kt) {
        const float4 x = h[2 * kt], y = h[2 * kt + 1];
        a[kt] = __builtin_bit_cast(bf16x8, (uint4){pk2bf(x.x, x.y), pk2bf(x.z, x.w),
                                                   pk2bf(y.x, y.y), pk2bf(y.z, y.w)});
    }
}

// ---- projection: q/k/v^T = W^T @ H^T (B-frags from swizzled sh_wt); K/V -> LDS, Q packed
__device__ __forceinline__ void proj_store(const short* __restrict__ sh_wt, const bf16x8 a[4],
                                           int lo, int hi, int w,
                                           short* __restrict__ sh_k, short* __restrict__ sh_vt,
                                           unsigned q_pk[4]) {
    f32x4 q_[2], k_[2], v_[2];
    #pragma unroll
    for (int nt = 0; nt < 2; ++nt)
        q_[nt] = k_[nt] = v_[nt] = (f32x4){0.f, 0.f, 0.f, 0.f};
    const int swz = (lo & 7) << 3;
    int col[4];
    #pragma unroll
    for (int kt = 0; kt < 4; ++kt) col[kt] = (kt * 32 + hi * 8) ^ swz;
    const short* wrow = sh_wt + lo * 128;
    #pragma unroll
    for (int nt = 0; nt < 2; ++nt) {
        const short* p0 = wrow + nt * 2048;
        #pragma unroll
        for (int kt = 0; kt < 4; ++kt) {
            const bf16x8 wq = *(const bf16x8*)(p0 + col[kt]);
            const bf16x8 wk = *(const bf16x8*)(p0 + 4096 + col[kt]);
            const bf16x8 wv = *(const bf16x8*)(p0 + 8192 + col[kt]);
            q_[nt] = __builtin_amdgcn_mfma_f32_16x16x32_bf16(wq, a[kt], q_[nt], 0, 0, 0);
            k_[nt] = __builtin_amdgcn_mfma_f32_16x16x32_bf16(wk, a[kt], k_[nt], 0, 0, 0);
            v_[nt] = __builtin_amdgcn_mfma_f32_16x16x32_bf16(wv, a[kt], v_[nt], 0, 0, 0);
        }
    }
    #pragma unroll
    for (int nt = 0; nt < 2; ++nt) {
        *(uint2*)&sh_k[(w * 16 + lo) * LDK + nt * 16 + hi * 4] =
            (uint2){pk2bf(k_[nt][0], k_[nt][1]), pk2bf(k_[nt][2], k_[nt][3])};
        #pragma unroll
        for (int j = 0; j < 4; ++j)
            sh_vt[(nt * 16 + hi * 4 + j) * LDVT + w * 16 + lo] = (short)f2bfu(v_[nt][j]);
        q_pk[nt * 2]     = pk2bf(q_[nt][0], q_[nt][1]);
        q_pk[nt * 2 + 1] = pk2bf(q_[nt][2], q_[nt][3]);
    }
}

// ---- mem-gate exps (packed bf16 pairs), unnormalized (1/l cancels in cosine)
__device__ __forceinline__ void gate_pd(const float* __restrict__ G2, float2 in2, unsigned pd[10]) {
    #pragma unroll
    for (int kp = 0; kp < 10; ++kp) {
        const float4 g = *(const float4*)(G2 + 4 * kp);
        pd[kp] = pk2bf(__expf(in2.x * g.x + in2.y * g.y),
                       __expf(in2.x * g.z + in2.y * g.w));
    }
}

// ---- memories^T = bank^T @ P2^T (reg-only bpermute B-frag)
__device__ __forceinline__ void mem_read(const short* __restrict__ bankM,
                                         const unsigned pd[10], int lo, int hi, int w,
                                         f32x4 am[2]) {
    am[0] = am[1] = (f32x4){0.f, 0.f, 0.f, 0.f};
    const int addrD = (w * 16 + lo) * 4;
    unsigned Wd[10];
    #pragma unroll
    for (int u = 0; u < 10; ++u)
        Wd[u] = __builtin_amdgcn_ds_bpermute(addrD, (int)pd[u]);
    unsigned b[4];
    #pragma unroll
    for (int u = 0; u < 4; ++u) {
        const unsigned l_ = (hi == 0) ? Wd[u] : Wd[4 + u];
        const unsigned h_ = (u < 2) ? ((hi == 2) ? Wd[8 + u] : 0u) : 0u;
        b[u] = (hi < 2) ? l_ : h_;
    }
    const bf16x8 bp2 = __builtin_bit_cast(bf16x8, (uint4){b[0], b[1], b[2], b[3]});
    #pragma unroll
    for (int nt = 0; nt < 2; ++nt) {
        const bf16x8 ab = *(const bf16x8*)(bankM + (nt * 16 + lo) * 32 + hi * 8);
        am[nt] = __builtin_amdgcn_mfma_f32_16x16x32_bf16(ab, bp2, am[nt], 0, 0, 0);
    }
}

// ---- E + F + cosine + store for one unit
__device__ __forceinline__ void attend_store(
    const short* __restrict__ shk, const short* __restrict__ shv,
    const unsigned q_pk[4], const f32x4 am[2],
    int lo, int hi, int w, int A01, int A23, int addrA, int addrB,
    int bn, int e, float* __restrict__ out) {
    unsigned pw[4][2];
    {
        unsigned l0 = __builtin_amdgcn_ds_bpermute(A01, (int)q_pk[0]);
        unsigned h0_ = __builtin_amdgcn_ds_bpermute(A01, (int)q_pk[2]);
        unsigned l1 = __builtin_amdgcn_ds_bpermute(A01, (int)q_pk[1]);
        unsigned h1_ = __builtin_amdgcn_ds_bpermute(A01, (int)q_pk[3]);
        unsigned l2 = __builtin_amdgcn_ds_bpermute(A23, (int)q_pk[0]);
        unsigned h2_ = __builtin_amdgcn_ds_bpermute(A23, (int)q_pk[2]);
        unsigned l3 = __builtin_amdgcn_ds_bpermute(A23, (int)q_pk[1]);
        unsigned h3_ = __builtin_amdgcn_ds_bpermute(A23, (int)q_pk[3]);
        const bf16x8 bq = __builtin_bit_cast(bf16x8, (uint4){
            (hi < 2) ? l0 : h0_, (hi < 2) ? l1 : h1_,
            (hi < 2) ? l2 : h2_, (hi < 2) ? l3 : h3_});
        #pragma unroll
        for (int st = 0; st < 4; ++st) {
            const bf16x8 akf = *(const bf16x8*)&shk[(st * 16 + lo) * LDK + hi * 8];
            const f32x4 en = __builtin_amdgcn_mfma_f32_16x16x32_bf16(
                akf, bq, (f32x4){0.f, 0.f, 0.f, 0.f}, 0, 0, 0);
            pw[st][0] = pk2bf(__expf(en[0]), __expf(en[1]));
            pw[st][1] = pk2bf(__expf(en[2]), __expf(en[3]));
        }
    }
    f32x4 av[2];
    av[0] = av[1] = (f32x4){0.f, 0.f, 0.f, 0.f};
    {
        bf16x8 bp[2];
        #pragma unroll
        for (int kt = 0; kt < 2; ++kt) {
            unsigned wrd[4];
            #pragma unroll
            for (int uu = 0; uu < 4; ++uu) {
                const int adr = (uu < 2) ? addrA : addrB;
                const unsigned ev = __builtin_amdgcn_ds_bpermute(adr, (int)pw[2 * kt][uu & 1]);
                const unsigned od = __builtin_amdgcn_ds_bpermute(adr, (int)pw[2 * kt + 1][uu & 1]);
                wrd[uu] = (hi < 2) ? ev : od;
            }
            bp[kt] = __builtin_bit_cast(bf16x8, (uint4){wrd[0], wrd[1], wrd[2], wrd[3]});
        }
        #pragma unroll
        for (int nt = 0; nt < 2; ++nt)
            #pragma unroll
            for (int kt = 0; kt < 2; ++kt) {
                const bf16x8 avt = *(const bf16x8*)&shv[(nt * 16 + lo) * LDVT + kt * 32 + hi * 8];
                av[nt] = __builtin_amdgcn_mfma_f32_16x16x32_bf16(avt, bp[kt], av[nt], 0, 0, 0);
            }
    }
    float d = 0.f, na = 0.f, nb = 0.f;
    #pragma unroll
    for (int nt = 0; nt < 2; ++nt)
        #pragma unroll
        for (int j = 0; j < 4; ++j) {
            const float av_ = av[nt][j], am_ = am[nt][j];
            d  = fmaf(av_, am_, d);
            na = fmaf(av_, av_, na);
            nb = fmaf(am_, am_, nb);
        }
    d  += __shfl_xor(d, 16);  d  += __shfl_xor(d, 32);
    na += __shfl_xor(na, 16); na += __shfl_xor(na, 32);
    nb += __shfl_xor(nb, 16); nb += __shfl_xor(nb, 32);
    if (hi == 0) {
        const float denom = fmaxf(sqrtf(na), 1e-8f) * fmaxf(sqrtf(nb), 1e-8f);
        out[((size_t)bn * Tc + w * 16 + lo) * Ec + e] = d / denom;
    }
}

__global__ __launch_bounds__(256, 4) void mg_mfma(
    const float* __restrict__ input,    // [B,N,T,2]
    const float* __restrict__ hidden,   // [E,B,N,T,C]
    const short* __restrict__ wt_img,   // [E][3][32][128] bf16, row-swizzled
    const short* __restrict__ bankM,    // [32][32] bf16 (memory^T, K zero-padded)
    const float* __restrict__ G2,       // [20][2] fp32
    float* __restrict__ out)            // [B,N,T,1,E]
{
    __shared__ __align__(16) short sh_wt[12288];      // 24576 B
    __shared__ __align__(16) short sh_k [Tc * LDK];   //  5120 B (single buffer)
    __shared__ __align__(16) short sh_vt[Mc * LDVT];  //  4608 B -> 34304 B, 4 blocks/CU

    const int t    = threadIdx.x;
    const int w    = t >> 6;
    const int lane = t & 63;
    const int lo   = lane & 15;
    const int hi   = lane >> 4;
    const int e    = blockIdx.x >> 9;            // 2048 blocks: e = bid/512
    const int bnb  = (blockIdx.x & 511) * UNITS; // 8 consecutive bn per block

    const int A01   = (((hi & 1) * 32) + lo) << 2;
    const int A23   = A01 + 64;
    const int addrA = (((hi & 1) * 2 + 0) * 16 + lo) * 4;
    const int addrB = (((hi & 1) * 2 + 1) * 16 + lo) * 4;

    // ---- weight-slice DMA to LDS (6 x 4KB linear; image pre-swizzled) — once per 8 units
    {
        const short* gsrc = wt_img + (size_t)e * 12288 + w * 512 + lane * 8;
        short* ldst = sh_wt + w * 512;
        #pragma unroll
        for (int c = 0; c < 6; ++c)
            gload_lds16(gsrc + c * 2048, ldst + c * 2048);
    }

    // ---- all 8 units' gate inputs (tiny, L2-hot)
    float2 in2[UNITS];
    #pragma unroll
    for (int u = 0; u < UNITS; ++u)
        in2[u] = *(const float2*)(input + ((size_t)(bnb + u) * Tc + lane) * 2);

    const float* hbase = hidden + (((size_t)(e * 4096 + bnb)) * Tc + w * 16 + lo) * Cc + hi * 8;

    float4  h[8];
    bf16x8  a[4];
    unsigned q_pk[4];

    // ---- prologue: unit 0 hidden, convert (stalls under weight-DMA window), C(0)
    load_hidden(hbase, h);
    conv_a(h, a);
    __syncthreads();                         // sh_wt visible
    proj_store(sh_wt, a, lo, hi, w, sh_k, sh_vt, q_pk);
    __syncthreads();                         // K/V(0) ready

    // Per-unit steady state (r10-verified schedule):
    //   issue h(u+1) | D(u) + E/F(u) fill its latency window | convert | bar | C(u+1) | bar
#define PHASE(U, NOT_LAST) do {                                                   \
        if (NOT_LAST) load_hidden(hbase + (U + 1) * (Tc * Cc), h);                \
        unsigned pd[10];                                                          \
        gate_pd(G2, in2[U], pd);                                                  \
        f32x4 am[2];                                                              \
        mem_read(bankM, pd, lo, hi, w, am);                                       \
        attend_store(sh_k, sh_vt, q_pk, am, lo, hi, w, A01, A23, addrA, addrB,    \
                     bnb + U, e, out);                                            \
        if (NOT_LAST) {                                                           \
            conv_a(h, a);                                                         \
            __syncthreads();      /* WAR: all waves done reading K/V(U) */        \
            proj_store(sh_wt, a, lo, hi, w, sh_k, sh_vt, q_pk);                   \
            __syncthreads();      /* K/V(U+1) ready */                            \
        }                                                                         \
    } while (0)

    PHASE(0, 1);
    PHASE(1, 1);
    PHASE(2, 1);
    PHASE(3, 1);
    PHASE(4, 1);
    PHASE(5, 1);
    PHASE(6, 1);
    PHASE(7, 0);
#undef PHASE
}

extern "C" void kernel_launch(void* const* d_in, const int* in_sizes, int n_in,
                              void* d_out, int out_size, void* d_ws, size_t ws_size,
                              hipStream_t stream) {
    const float* input   = (const float*)d_in[0];
    const float* hidden  = (const float*)d_in[1];
    const float* membank = (const float*)d_in[2];
    const float* iq      = (const float*)d_in[3];
    const float* Wq      = (const float*)d_in[4];
    const float* Wk      = (const float*)d_in[5];
    const float* Wv      = (const float*)d_in[6];
    float* out = (float*)d_out;

    short* wt_img = (short*)d_ws;                      // 98304 B
    short* bankM  = (short*)((char*)d_ws + 98304);     //  2048 B
    float* G2     = (float*)((char*)d_ws + 100352);    //   160 B

    prep<<<193, 256, 0, stream>>>(Wq, Wk, Wv, membank, iq, wt_img, bankM, G2);
    mg_mfma<<<Ec * Bc * Nc / UNITS, 256, 0, stream>>>(input, hidden, wt_img, bankM, G2, out);
}